// Round 13
// baseline (171.947 us; speedup 1.0000x reference)
//
#include <hip/hip_runtime.h>

// ---------------------------------------------------------------------------
// GCN forward. Fused front-end (binA-direct || gemm1) + binB exact-CSR +
// split-pipelined tail: agg1A -> (agg1B || gemm2A) -> gemm2B -> agg2.
//   h1 = relu(segsum(ew * (x@W1)[src] -> dst) + b1)    128 -> 128
//   h2 = relu(segsum(ew * (h1@W2)[src] -> dst) + b2)   128 -> 64
// S2 lives in the ebuf region (dead after binB) so gemm2A can run while
// agg1B still gathers from S.
// ---------------------------------------------------------------------------

typedef __attribute__((ext_vector_type(8))) short bf16x8;
typedef __attribute__((ext_vector_type(4))) float f32x4;

#define CAPB 12288     // per-bucket ebuf capacity (bucket mean 8163, sigma 90)
#define PADCAP 4096    // per-bucket csr pad slack (512 nodes * 8)

__device__ __forceinline__ ushort f2bf(float f) {
    uint u = __float_as_uint(f);
    u += 0x7fff + ((u >> 16) & 1);   // round-to-nearest-even
    return (ushort)(u >> 16);
}
__device__ __forceinline__ float bf_lo(uint bits) { return __uint_as_float(bits << 16); }
__device__ __forceinline__ float bf_hi(uint bits) { return __uint_as_float(bits & 0xffff0000u); }

// ---- W1,W2 -> bf16 transposed [n][k]; block 0 also zeroes ccur -------------
__global__ __launch_bounds__(256) void wconv_kernel(const float* __restrict__ W1,
                                                    ushort* __restrict__ Wt1,
                                                    const float* __restrict__ W2,
                                                    ushort* __restrict__ Wt2,
                                                    int* __restrict__ ccur) {
    if (blockIdx.x == 0) ccur[threadIdx.x] = 0;
    int i = blockIdx.x * 256 + threadIdx.x;
    if (i < 128 * 128) {
        int k = i >> 7, n = i & 127;
        Wt1[n * 128 + k] = f2bf(W1[i]);
    } else {
        int i2 = i - 128 * 128;
        if (i2 < 128 * 64) {
            int k = i2 >> 6, n = i2 & 63;
            Wt2[n * 128 + k] = f2bf(W2[i2]);
        }
    }
}

// ---- GEMM1 body (BN=128, A=f32): one 128x128 row tile ----------------------
__device__ __forceinline__ void gemm1_body(const float* __restrict__ A,
                                           const ushort* __restrict__ Wt,
                                           ushort* __restrict__ C, int M,
                                           int rowblk, char* smem) {
    const int tid = threadIdx.x;
    const int m0 = rowblk * 128;

    #pragma unroll
    for (int it = 0; it < 8; ++it) {
        int c = tid + it * 256;
        int r = c >> 4;
        int k8 = (c & 15) << 3;
        int row = m0 + r;
        uint4 w4 = make_uint4(0u, 0u, 0u, 0u);
        if (row < M) {
            float4 v0 = *(const float4*)(A + (size_t)row * 128 + k8);
            float4 v1 = *(const float4*)(A + (size_t)row * 128 + k8 + 4);
            w4.x = (uint)f2bf(v0.x) | ((uint)f2bf(v0.y) << 16);
            w4.y = (uint)f2bf(v0.z) | ((uint)f2bf(v0.w) << 16);
            w4.z = (uint)f2bf(v1.x) | ((uint)f2bf(v1.y) << 16);
            w4.w = (uint)f2bf(v1.z) | ((uint)f2bf(v1.w) << 16);
        }
        int byte = (r * 256 + k8 * 2) ^ ((r & 7) << 4);
        *(uint4*)(smem + byte) = w4;
    }
    __syncthreads();

    const int wid = tid >> 6, lane = tid & 63;
    const int wy = wid >> 1;
    const int wx = wid & 1;
    const int rb = wy * 64;
    const int cb = wx * 64;
    const int ln = lane & 15;
    const int kg = lane >> 4;

    f32x4 acc[4][4];
    #pragma unroll
    for (int i = 0; i < 4; ++i)
        #pragma unroll
        for (int j = 0; j < 4; ++j) acc[i][j] = (f32x4){0.f, 0.f, 0.f, 0.f};

    #pragma unroll
    for (int s = 0; s < 4; ++s) {
        bf16x8 b[4];
        #pragma unroll
        for (int j = 0; j < 4; ++j)
            b[j] = *(const bf16x8*)(Wt + (size_t)(cb + j * 16 + ln) * 128 + s * 32 + kg * 8);
        bf16x8 a[4];
        #pragma unroll
        for (int i = 0; i < 4; ++i) {
            int r = rb + i * 16 + ln;
            int byte = (r * 256 + s * 64 + kg * 16) ^ ((r & 7) << 4);
            a[i] = *(const bf16x8*)(smem + byte);
        }
        #pragma unroll
        for (int i = 0; i < 4; ++i)
            #pragma unroll
            for (int j = 0; j < 4; ++j)
                acc[i][j] = __builtin_amdgcn_mfma_f32_16x16x32_bf16(a[i], b[j], acc[i][j], 0, 0, 0);
    }

    #pragma unroll
    for (int i = 0; i < 4; ++i)
        #pragma unroll
        for (int q = 0; q < 4; ++q) {
            int row = m0 + rb + i * 16 + kg * 4 + q;
            if (row < M) {
                #pragma unroll
                for (int j = 0; j < 4; ++j)
                    C[(size_t)row * 128 + cb + j * 16 + ln] = f2bf(acc[i][j][q]);
            }
        }
}

// ---- binA-direct body: LDS counting-sort of a 4096-edge chunk into coarse
// buckets; per-bucket bump allocation into fixed CAPB regions of ebuf.
__device__ __forceinline__ void binA_body(const int* __restrict__ src,
                                          const int* __restrict__ dst,
                                          const float* __restrict__ ew,
                                          int* __restrict__ ccur,
                                          uint2* __restrict__ ebuf, int E,
                                          char* smem) {
    uint2* stage = (uint2*)smem;                            // 32768 B
    int* lh   = (int*)(smem + 32768);                       // 1 KB
    int* loff = (int*)(smem + 33792);                       // 1 KB
    int* gpos = (int*)(smem + 34816);                       // 1 KB
    unsigned char* sbuck = (unsigned char*)(smem + 35840);  // 4 KB
    const int tid = threadIdx.x;
    const int base = blockIdx.x * 4096;
    const int nn = min(4096, E - base);

    lh[tid] = 0;
    __syncthreads();

    uint pk[16], wb[16];
    short bk[16], rk[16];
    #pragma unroll
    for (int i = 0; i < 16; ++i) {
        int li = tid + i * 256;
        bk[i] = -1;
        if (li < nn) {
            int e = base + li;
            int d = dst[e];
            int b = d >> 9;
            pk[i] = (uint)src[e] | ((uint)(d & 511) << 17);
            wb[i] = __float_as_uint(ew[e]);
            bk[i] = (short)b;
            rk[i] = (short)atomicAdd(&lh[b], 1);
        }
    }
    __syncthreads();

    int v = lh[tid];
    loff[tid] = v;
    __syncthreads();
    #pragma unroll
    for (int off = 1; off < 256; off <<= 1) {
        int t = (tid >= off) ? loff[tid - off] : 0;
        __syncthreads();
        loff[tid] += t;
        __syncthreads();
    }
    int excl = loff[tid] - v;
    __syncthreads();
    loff[tid] = excl;
    gpos[tid] = (v > 0) ? atomicAdd(&ccur[tid], v) : 0;   // offset within bucket region
    __syncthreads();

    #pragma unroll
    for (int i = 0; i < 16; ++i)
        if (bk[i] >= 0) {
            int s = loff[bk[i]] + rk[i];
            stage[s] = make_uint2(pk[i], wb[i]);
            sbuck[s] = (unsigned char)bk[i];
        }
    __syncthreads();

    for (int s = tid; s < nn; s += 256) {
        uint2 e2 = stage[s];
        int b = sbuck[s];
        ebuf[(size_t)b * CAPB + gpos[b] + (s - loff[b])] = e2;
    }
}

// Fused front-end: first csrB blocks run binA-direct, the rest gemm1 tiles.
__global__ __launch_bounds__(256) void fused_kernel(int csrB,
        const int* __restrict__ src, const int* __restrict__ dst,
        const float* __restrict__ ew, int* __restrict__ ccur,
        uint2* __restrict__ ebuf, int E,
        const float* __restrict__ x, const ushort* __restrict__ Wt1,
        ushort* __restrict__ S, int M) {
    __shared__ alignas(16) char smem[40960];
    if ((int)blockIdx.x < csrB)
        binA_body(src, dst, ew, ccur, ebuf, E, smem);
    else
        gemm1_body(x, Wt1, S, M, (int)blockIdx.x - csrB, smem);
}

// ---- GEMM2 body (BN=64, A=bf16): one 128-row tile --------------------------
__device__ __forceinline__ void gemm2_body(const ushort* __restrict__ Av,
                                           const ushort* __restrict__ Wt,
                                           ushort* __restrict__ C, int M,
                                           int rowblk, char* smem) {
    const int tid = threadIdx.x;
    const int m0 = rowblk * 128;

    #pragma unroll
    for (int it = 0; it < 8; ++it) {
        int c = tid + it * 256;
        int r = c >> 4;
        int k8 = (c & 15) << 3;
        int row = m0 + r;
        uint4 w4 = make_uint4(0u, 0u, 0u, 0u);
        if (row < M)
            w4 = *(const uint4*)(Av + (size_t)row * 128 + k8);
        int byte = (r * 256 + k8 * 2) ^ ((r & 7) << 4);
        *(uint4*)(smem + byte) = w4;
    }
    __syncthreads();

    const int wid = tid >> 6, lane = tid & 63;
    const int rb = wid * 32;
    const int ln = lane & 15;
    const int kg = lane >> 4;

    f32x4 acc[2][4];
    #pragma unroll
    for (int i = 0; i < 2; ++i)
        #pragma unroll
        for (int j = 0; j < 4; ++j) acc[i][j] = (f32x4){0.f, 0.f, 0.f, 0.f};

    #pragma unroll
    for (int s = 0; s < 4; ++s) {
        bf16x8 b[4];
        #pragma unroll
        for (int j = 0; j < 4; ++j)
            b[j] = *(const bf16x8*)(Wt + (size_t)(j * 16 + ln) * 128 + s * 32 + kg * 8);
        bf16x8 a[2];
        #pragma unroll
        for (int i = 0; i < 2; ++i) {
            int r = rb + i * 16 + ln;
            int byte = (r * 256 + s * 64 + kg * 16) ^ ((r & 7) << 4);
            a[i] = *(const bf16x8*)(smem + byte);
        }
        #pragma unroll
        for (int i = 0; i < 2; ++i)
            #pragma unroll
            for (int j = 0; j < 4; ++j)
                acc[i][j] = __builtin_amdgcn_mfma_f32_16x16x32_bf16(a[i], b[j], acc[i][j], 0, 0, 0);
    }

    #pragma unroll
    for (int i = 0; i < 2; ++i)
        #pragma unroll
        for (int q = 0; q < 4; ++q) {
            int row = m0 + rb + i * 16 + kg * 4 + q;
            if (row < M) {
                #pragma unroll
                for (int j = 0; j < 4; ++j)
                    C[(size_t)row * 64 + j * 16 + ln] = f2bf(acc[i][j][q]);
            }
        }
}

__global__ __launch_bounds__(256) void gemm2_kernel(const ushort* __restrict__ Av,
                                                    const ushort* __restrict__ Wt,
                                                    ushort* __restrict__ C, int M,
                                                    int gOff) {
    __shared__ alignas(16) char smem[32768];
    gemm2_body(Av, Wt, C, M, gOff + (int)blockIdx.x, smem);
}

// binB: one block per coarse bucket. Fine-histogram + padded scan ->
// rstart/pdeg; exact placement; dummy fill. Bucket count comes from ccur.
__global__ __launch_bounds__(512) void binB_kernel(const uint2* __restrict__ ebuf,
                                                   const int* __restrict__ ccur,
                                                   int* __restrict__ rstart,
                                                   int* __restrict__ pdeg,
                                                   int2* __restrict__ csr, int N) {
    __shared__ int fh[512];
    __shared__ int pp[512];
    __shared__ int cur[512];
    const int c = blockIdx.x;
    const int tid = threadIdx.x;
    const int n0 = c << 9;
    const int cbase = c * CAPB;                    // ebuf region base
    const int cend = cbase + ccur[c];              // + bucket count
    const int pbase = c * (CAPB + PADCAP);         // csr region base

    fh[tid] = 0;
    __syncthreads();
    for (int e = cbase + tid; e < cend; e += 512)
        atomicAdd(&fh[ebuf[e].x >> 17], 1);
    __syncthreads();

    int cnt = fh[tid];
    int p = (cnt + 7) & ~7;          // pad rows to multiple of 8
    pp[tid] = p;
    __syncthreads();
    #pragma unroll
    for (int off = 1; off < 512; off <<= 1) {
        int t = (tid >= off) ? pp[tid - off] : 0;
        __syncthreads();
        pp[tid] += t;
        __syncthreads();
    }
    int r = pbase + pp[tid] - p;   // padded exclusive position
    if (n0 + tid < N) {
        rstart[n0 + tid] = r;
        pdeg[n0 + tid] = p;
    }
    cur[tid] = r;
    __syncthreads();

    for (int e = cbase + tid; e < cend; e += 512) {
        uint2 u = ebuf[e];
        int fine = u.x >> 17;
        int pos = atomicAdd(&cur[fine], 1);
        csr[pos] = make_int2((int)(u.x & 0x1FFFF), (int)u.y);
    }
    __syncthreads();

    // dummy fill (src=0, w=0) up to padded end
    for (int k = cur[tid]; k < r + p; ++k)
        csr[k] = make_int2(0, 0);
}

// ---- Aggregation body: NPW nodes per wave (split-wave), node range [n0,n1) -
template <int F, int NPW, bool OBF>
__device__ __forceinline__ void agg_body(const ushort* __restrict__ sup,
                                         const int* __restrict__ rstart,
                                         const int* __restrict__ pdeg,
                                         const int2* __restrict__ csr,
                                         const float* __restrict__ bias,
                                         void* __restrict__ outp,
                                         int n0, int n1, int bid) {
    constexpr int LPN = 64 / NPW;    // lanes per node
    constexpr int LPR = F / 8;       // lanes per row
    static_assert(LPN / LPR == 2, "two slot-groups per node");
    const int lane = threadIdx.x & 63;
    const int wbase = n0 + ((bid * 256 + (int)threadIdx.x) >> 6) * NPW;
    if (wbase >= n1) return;
    const int sub = lane / LPN;
    const int grp = (lane % LPN) / LPR;
    const int cl  = lane % LPR;
    const int node = wbase + sub;
    const bool nvalid = node < n1;
    const int nidx = nvalid ? node : n0;
    const int rs = rstart[nidx];
    const int pd = nvalid ? pdeg[nidx] : 0;

    int pmax = pd;
    #pragma unroll
    for (int off = LPN; off < 64; off <<= 1)
        pmax = max(pmax, __shfl_xor(pmax, off));
    pmax = __builtin_amdgcn_readfirstlane(pmax);

    const ushort* rp = sup + cl * 8;
    float acc[8] = {0.f, 0.f, 0.f, 0.f, 0.f, 0.f, 0.f, 0.f};

    for (int j = 0; j < pmax; j += 16) {
        int2 m[8];
        #pragma unroll
        for (int t = 0; t < 8; ++t) {
            int slot = j + t * 2 + grp;
            bool ok = slot < pd;
            m[t] = csr[rs + (ok ? slot : 0)];
            if (!ok) m[t].y = 0;
        }
        uint4 v[8];
        #pragma unroll
        for (int t = 0; t < 8; ++t)
            v[t] = *(const uint4*)(rp + (size_t)m[t].x * F);
        #pragma unroll
        for (int t = 0; t < 8; ++t) {
            float w = __int_as_float(m[t].y);
            uint4 q = v[t];
            acc[0] = fmaf(bf_lo(q.x), w, acc[0]); acc[1] = fmaf(bf_hi(q.x), w, acc[1]);
            acc[2] = fmaf(bf_lo(q.y), w, acc[2]); acc[3] = fmaf(bf_hi(q.y), w, acc[3]);
            acc[4] = fmaf(bf_lo(q.z), w, acc[4]); acc[5] = fmaf(bf_hi(q.z), w, acc[5]);
            acc[6] = fmaf(bf_lo(q.w), w, acc[6]); acc[7] = fmaf(bf_hi(q.w), w, acc[7]);
        }
    }

    // fold the two slot-groups of each node (lanes differ by LPR)
    #pragma unroll
    for (int i = 0; i < 8; ++i) acc[i] += __shfl_xor(acc[i], LPR);

    if (grp == 0 && nvalid) {
        float4 b0 = ((const float4*)bias)[cl * 2 + 0];
        float4 b1 = ((const float4*)bias)[cl * 2 + 1];
        acc[0] = fmaxf(acc[0] + b0.x, 0.f); acc[1] = fmaxf(acc[1] + b0.y, 0.f);
        acc[2] = fmaxf(acc[2] + b0.z, 0.f); acc[3] = fmaxf(acc[3] + b0.w, 0.f);
        acc[4] = fmaxf(acc[4] + b1.x, 0.f); acc[5] = fmaxf(acc[5] + b1.y, 0.f);
        acc[6] = fmaxf(acc[6] + b1.z, 0.f); acc[7] = fmaxf(acc[7] + b1.w, 0.f);
        if (OBF) {
            uint4 o;
            o.x = (uint)f2bf(acc[0]) | ((uint)f2bf(acc[1]) << 16);
            o.y = (uint)f2bf(acc[2]) | ((uint)f2bf(acc[3]) << 16);
            o.z = (uint)f2bf(acc[4]) | ((uint)f2bf(acc[5]) << 16);
            o.w = (uint)f2bf(acc[6]) | ((uint)f2bf(acc[7]) << 16);
            ((uint4*)outp)[(size_t)node * LPR + cl] = o;
        } else {
            ((float4*)outp)[(size_t)node * LPR * 2 + cl * 2 + 0] =
                make_float4(acc[0], acc[1], acc[2], acc[3]);
            ((float4*)outp)[(size_t)node * LPR * 2 + cl * 2 + 1] =
                make_float4(acc[4], acc[5], acc[6], acc[7]);
        }
    }
}

template <int F, int NPW, bool OBF>
__global__ __launch_bounds__(256) void agg_kernel(const ushort* __restrict__ sup,
                                                  const int* __restrict__ rstart,
                                                  const int* __restrict__ pdeg,
                                                  const int2* __restrict__ csr,
                                                  const float* __restrict__ bias,
                                                  void* __restrict__ outp,
                                                  int n0, int n1) {
    agg_body<F, NPW, OBF>(sup, rstart, pdeg, csr, bias, outp, n0, n1, (int)blockIdx.x);
}

// Fused tail: first aggB blocks run agg1 on nodes [NA,N); the rest run gemm2
// tiles [0, NA/128) writing S2 (in the dead ebuf region).
__global__ __launch_bounds__(256) void fused_tail(int aggB, int NA, int N,
        const ushort* __restrict__ S, const int* __restrict__ rstart,
        const int* __restrict__ pdeg, const int2* __restrict__ csr,
        const float* __restrict__ b1, ushort* __restrict__ H1b,
        const ushort* __restrict__ Wt2, ushort* __restrict__ S2) {
    __shared__ alignas(16) char smem[32768];
    if ((int)blockIdx.x < aggB)
        agg_body<128, 2, true>(S, rstart, pdeg, csr, b1, H1b, NA, N, (int)blockIdx.x);
    else
        gemm2_body(H1b, Wt2, S2, N, (int)blockIdx.x - aggB, smem);
}

extern "C" void kernel_launch(void* const* d_in, const int* in_sizes, int n_in,
                              void* d_out, int out_size, void* d_ws, size_t ws_size,
                              hipStream_t stream) {
    const float* x  = (const float*)d_in[0];
    const int*   ei = (const int*)d_in[1];
    const float* ew = (const float*)d_in[2];
    const float* W1 = (const float*)d_in[3];
    const float* b1 = (const float*)d_in[4];
    const float* W2 = (const float*)d_in[5];
    const float* b2 = (const float*)d_in[6];
    float* out = (float*)d_out;

    const int N = in_sizes[0] / 128;     // 100000
    const int E = in_sizes[2];           // 1600000
    const int* src = ei;
    const int* dst = ei + E;
    const int NCB = (N + 511) / 512;     // 196 coarse buckets (<= 256)
    const int GB = (N + 127) / 128;      // 782 gemm tiles
    const int NBA = (E + 4095) / 4096;   // 391 binA blocks

    char* ws = (char*)d_ws;
    size_t o = 0;
    ushort* S      = (ushort*)(ws + o); o += (size_t)N * 128 * sizeof(ushort);
    ushort* H1b    = (ushort*)(ws + o); o += (size_t)N * 128 * sizeof(ushort);
    uint2*  ebuf   = (uint2*) (ws + o); o += (size_t)NCB * CAPB * sizeof(uint2);
    int2*   csr    = (int2*)  (ws + o); o += (size_t)NCB * (CAPB + PADCAP) * sizeof(int2);
    int*    rstart = (int*)   (ws + o); o += (size_t)N * sizeof(int);
    int*    pdeg   = (int*)   (ws + o); o += (size_t)N * sizeof(int);
    int*    ccur   = (int*)   (ws + o); o += 256 * sizeof(int);
    ushort* Wt1    = (ushort*)(ws + o); o += 128 * 128 * sizeof(ushort);
    ushort* Wt2    = (ushort*)(ws + o); o += 128 * 64 * sizeof(ushort);
    ushort* S2     = (ushort*)ebuf;     // dead after binB; N*64 bf16 fits

    // Pipeline split point: ~60% of nodes, tile-aligned.
    const int NA = ((N * 3 / 5) / 128) * 128;      // 59904 for N=100000
    const int TA = NA / 128;                        // gemm2A tiles
    const int aggB = (N - NA + 7) / 8;              // agg1B blocks

    // ---- weights -> bf16 transposed; zero bump cursors ----
    wconv_kernel<<<96, 256, 0, stream>>>(W1, Wt1, W2, Wt2, ccur);

    // ---- fused front-end: binA-direct || gemm1 (all tiles) ----
    fused_kernel<<<NBA + GB, 256, 0, stream>>>(NBA, src, dst, ew, ccur,
                                               ebuf, E, x, Wt1, S, N);
    binB_kernel<<<NCB, 512, 0, stream>>>(ebuf, ccur, rstart, pdeg, csr, N);

    // ---- agg1A: nodes [0, NA) ----
    agg_kernel<128, 2, true><<<NA / 8, 256, 0, stream>>>(S, rstart, pdeg, csr,
                                                         b1, H1b, 0, NA);
    // ---- agg1B (nodes [NA,N)) || gemm2A (tiles [0,TA) -> S2) ----
    fused_tail<<<aggB + TA, 256, 0, stream>>>(aggB, NA, N, S, rstart, pdeg, csr,
                                              b1, H1b, Wt2, S2);
    // ---- gemm2B: remaining tiles ----
    gemm2_kernel<<<GB - TA, 256, 0, stream>>>(H1b, Wt2, S2, N, TA);

    // ---- layer 2 aggregation ----
    agg_kernel<64, 4, false><<<(N + 15) / 16, 256, 0, stream>>>(S2, rstart, pdeg,
                                                                csr, b2, out, 0, N);
}

// Round 14
// 162.111 us; speedup vs baseline: 1.0607x; 1.0607x over previous
//
#include <hip/hip_runtime.h>

// ---------------------------------------------------------------------------
// GCN forward. Single fused front-end: binA-direct (per-bucket bump alloc,
// no chist/cscan) co-scheduled with ALL of GEMM1; binB exact-CSR; split-wave
// gather aggregation; bf16 MFMA GEMMs.
//   h1 = relu(segsum(ew * (x@W1)[src] -> dst) + b1)    128 -> 128
//   h2 = relu(segsum(ew * (h1@W2)[src] -> dst) + b2)   128 -> 64
// (R14 = revert to R12 exactly: R13's tail-overlap refactor perturbed the
// untouched fused_kernel's codegen (+18 us) and the range-split agg (-14%).)
// ---------------------------------------------------------------------------

typedef __attribute__((ext_vector_type(8))) short bf16x8;
typedef __attribute__((ext_vector_type(4))) float f32x4;

#define CAPB 12288     // per-bucket ebuf capacity (bucket mean 8163, sigma 90)
#define PADCAP 4096    // per-bucket csr pad slack (512 nodes * 8)

__device__ __forceinline__ ushort f2bf(float f) {
    uint u = __float_as_uint(f);
    u += 0x7fff + ((u >> 16) & 1);   // round-to-nearest-even
    return (ushort)(u >> 16);
}
__device__ __forceinline__ float bf_lo(uint bits) { return __uint_as_float(bits << 16); }
__device__ __forceinline__ float bf_hi(uint bits) { return __uint_as_float(bits & 0xffff0000u); }

// ---- W1,W2 -> bf16 transposed [n][k]; block 0 also zeroes ccur -------------
__global__ __launch_bounds__(256) void wconv_kernel(const float* __restrict__ W1,
                                                    ushort* __restrict__ Wt1,
                                                    const float* __restrict__ W2,
                                                    ushort* __restrict__ Wt2,
                                                    int* __restrict__ ccur) {
    if (blockIdx.x == 0) ccur[threadIdx.x] = 0;
    int i = blockIdx.x * 256 + threadIdx.x;
    if (i < 128 * 128) {
        int k = i >> 7, n = i & 127;
        Wt1[n * 128 + k] = f2bf(W1[i]);
    } else {
        int i2 = i - 128 * 128;
        if (i2 < 128 * 64) {
            int k = i2 >> 6, n = i2 & 63;
            Wt2[n * 128 + k] = f2bf(W2[i2]);
        }
    }
}

// ---- GEMM body (BN=128, A=f32): one 128x128 row tile -----------------------
__device__ __forceinline__ void gemm1_body(const float* __restrict__ A,
                                           const ushort* __restrict__ Wt,
                                           ushort* __restrict__ C, int M,
                                           int rowblk, char* smem) {
    const int tid = threadIdx.x;
    const int m0 = rowblk * 128;

    #pragma unroll
    for (int it = 0; it < 8; ++it) {
        int c = tid + it * 256;
        int r = c >> 4;
        int k8 = (c & 15) << 3;
        int row = m0 + r;
        uint4 w4 = make_uint4(0u, 0u, 0u, 0u);
        if (row < M) {
            float4 v0 = *(const float4*)(A + (size_t)row * 128 + k8);
            float4 v1 = *(const float4*)(A + (size_t)row * 128 + k8 + 4);
            w4.x = (uint)f2bf(v0.x) | ((uint)f2bf(v0.y) << 16);
            w4.y = (uint)f2bf(v0.z) | ((uint)f2bf(v0.w) << 16);
            w4.z = (uint)f2bf(v1.x) | ((uint)f2bf(v1.y) << 16);
            w4.w = (uint)f2bf(v1.z) | ((uint)f2bf(v1.w) << 16);
        }
        int byte = (r * 256 + k8 * 2) ^ ((r & 7) << 4);
        *(uint4*)(smem + byte) = w4;
    }
    __syncthreads();

    const int wid = tid >> 6, lane = tid & 63;
    const int wy = wid >> 1;
    const int wx = wid & 1;
    const int rb = wy * 64;
    const int cb = wx * 64;
    const int ln = lane & 15;
    const int kg = lane >> 4;

    f32x4 acc[4][4];
    #pragma unroll
    for (int i = 0; i < 4; ++i)
        #pragma unroll
        for (int j = 0; j < 4; ++j) acc[i][j] = (f32x4){0.f, 0.f, 0.f, 0.f};

    #pragma unroll
    for (int s = 0; s < 4; ++s) {
        bf16x8 b[4];
        #pragma unroll
        for (int j = 0; j < 4; ++j)
            b[j] = *(const bf16x8*)(Wt + (size_t)(cb + j * 16 + ln) * 128 + s * 32 + kg * 8);
        bf16x8 a[4];
        #pragma unroll
        for (int i = 0; i < 4; ++i) {
            int r = rb + i * 16 + ln;
            int byte = (r * 256 + s * 64 + kg * 16) ^ ((r & 7) << 4);
            a[i] = *(const bf16x8*)(smem + byte);
        }
        #pragma unroll
        for (int i = 0; i < 4; ++i)
            #pragma unroll
            for (int j = 0; j < 4; ++j)
                acc[i][j] = __builtin_amdgcn_mfma_f32_16x16x32_bf16(a[i], b[j], acc[i][j], 0, 0, 0);
    }

    #pragma unroll
    for (int i = 0; i < 4; ++i)
        #pragma unroll
        for (int q = 0; q < 4; ++q) {
            int row = m0 + rb + i * 16 + kg * 4 + q;
            if (row < M) {
                #pragma unroll
                for (int j = 0; j < 4; ++j)
                    C[(size_t)row * 128 + cb + j * 16 + ln] = f2bf(acc[i][j][q]);
            }
        }
}

// ---- binA-direct body: LDS counting-sort of a 4096-edge chunk into coarse
// buckets; per-bucket bump allocation into fixed CAPB regions of ebuf.
__device__ __forceinline__ void binA_body(const int* __restrict__ src,
                                          const int* __restrict__ dst,
                                          const float* __restrict__ ew,
                                          int* __restrict__ ccur,
                                          uint2* __restrict__ ebuf, int E,
                                          char* smem) {
    uint2* stage = (uint2*)smem;                            // 32768 B
    int* lh   = (int*)(smem + 32768);                       // 1 KB
    int* loff = (int*)(smem + 33792);                       // 1 KB
    int* gpos = (int*)(smem + 34816);                       // 1 KB
    unsigned char* sbuck = (unsigned char*)(smem + 35840);  // 4 KB
    const int tid = threadIdx.x;
    const int base = blockIdx.x * 4096;
    const int nn = min(4096, E - base);

    lh[tid] = 0;
    __syncthreads();

    uint pk[16], wb[16];
    short bk[16], rk[16];
    #pragma unroll
    for (int i = 0; i < 16; ++i) {
        int li = tid + i * 256;
        bk[i] = -1;
        if (li < nn) {
            int e = base + li;
            int d = dst[e];
            int b = d >> 9;
            pk[i] = (uint)src[e] | ((uint)(d & 511) << 17);
            wb[i] = __float_as_uint(ew[e]);
            bk[i] = (short)b;
            rk[i] = (short)atomicAdd(&lh[b], 1);
        }
    }
    __syncthreads();

    int v = lh[tid];
    loff[tid] = v;
    __syncthreads();
    #pragma unroll
    for (int off = 1; off < 256; off <<= 1) {
        int t = (tid >= off) ? loff[tid - off] : 0;
        __syncthreads();
        loff[tid] += t;
        __syncthreads();
    }
    int excl = loff[tid] - v;
    __syncthreads();
    loff[tid] = excl;
    gpos[tid] = (v > 0) ? atomicAdd(&ccur[tid], v) : 0;   // offset within bucket region
    __syncthreads();

    #pragma unroll
    for (int i = 0; i < 16; ++i)
        if (bk[i] >= 0) {
            int s = loff[bk[i]] + rk[i];
            stage[s] = make_uint2(pk[i], wb[i]);
            sbuck[s] = (unsigned char)bk[i];
        }
    __syncthreads();

    for (int s = tid; s < nn; s += 256) {
        uint2 e2 = stage[s];
        int b = sbuck[s];
        ebuf[(size_t)b * CAPB + gpos[b] + (s - loff[b])] = e2;
    }
}

// Fused front-end: first csrB blocks run binA-direct, the rest gemm1 tiles.
__global__ __launch_bounds__(256) void fused_kernel(int csrB,
        const int* __restrict__ src, const int* __restrict__ dst,
        const float* __restrict__ ew, int* __restrict__ ccur,
        uint2* __restrict__ ebuf, int E,
        const float* __restrict__ x, const ushort* __restrict__ Wt1,
        ushort* __restrict__ S, int M) {
    __shared__ alignas(16) char smem[40960];
    if ((int)blockIdx.x < csrB)
        binA_body(src, dst, ew, ccur, ebuf, E, smem);
    else
        gemm1_body(x, Wt1, S, M, (int)blockIdx.x - csrB, smem);
}

// ---- standalone GEMM (layer 2: BN=64, A=bf16) ------------------------------
__global__ __launch_bounds__(256) void gemm_mfma64(const ushort* __restrict__ Av,
                                                   const ushort* __restrict__ Wt,
                                                   ushort* __restrict__ C, int M) {
    __shared__ ushort As[128 * 128];
    const int tid = threadIdx.x;
    const int m0 = blockIdx.x * 128;

    #pragma unroll
    for (int it = 0; it < 8; ++it) {
        int c = tid + it * 256;
        int r = c >> 4;
        int k8 = (c & 15) << 3;
        int row = m0 + r;
        uint4 w4 = make_uint4(0u, 0u, 0u, 0u);
        if (row < M)
            w4 = *(const uint4*)(Av + (size_t)row * 128 + k8);
        int byte = (r * 256 + k8 * 2) ^ ((r & 7) << 4);
        *(uint4*)((char*)As + byte) = w4;
    }
    __syncthreads();

    const int wid = tid >> 6, lane = tid & 63;
    const int rb = wid * 32;
    const int ln = lane & 15;
    const int kg = lane >> 4;

    f32x4 acc[2][4];
    #pragma unroll
    for (int i = 0; i < 2; ++i)
        #pragma unroll
        for (int j = 0; j < 4; ++j) acc[i][j] = (f32x4){0.f, 0.f, 0.f, 0.f};

    #pragma unroll
    for (int s = 0; s < 4; ++s) {
        bf16x8 b[4];
        #pragma unroll
        for (int j = 0; j < 4; ++j)
            b[j] = *(const bf16x8*)(Wt + (size_t)(j * 16 + ln) * 128 + s * 32 + kg * 8);
        bf16x8 a[2];
        #pragma unroll
        for (int i = 0; i < 2; ++i) {
            int r = rb + i * 16 + ln;
            int byte = (r * 256 + s * 64 + kg * 16) ^ ((r & 7) << 4);
            a[i] = *(const bf16x8*)((const char*)As + byte);
        }
        #pragma unroll
        for (int i = 0; i < 2; ++i)
            #pragma unroll
            for (int j = 0; j < 4; ++j)
                acc[i][j] = __builtin_amdgcn_mfma_f32_16x16x32_bf16(a[i], b[j], acc[i][j], 0, 0, 0);
    }

    #pragma unroll
    for (int i = 0; i < 2; ++i)
        #pragma unroll
        for (int q = 0; q < 4; ++q) {
            int row = m0 + rb + i * 16 + kg * 4 + q;
            if (row < M) {
                #pragma unroll
                for (int j = 0; j < 4; ++j)
                    C[(size_t)row * 64 + j * 16 + ln] = f2bf(acc[i][j][q]);
            }
        }
}

// binB: one block per coarse bucket. Fine-histogram + padded scan ->
// rstart/pdeg; exact placement; dummy fill. Bucket count comes from ccur.
__global__ __launch_bounds__(512) void binB_kernel(const uint2* __restrict__ ebuf,
                                                   const int* __restrict__ ccur,
                                                   int* __restrict__ rstart,
                                                   int* __restrict__ pdeg,
                                                   int2* __restrict__ csr, int N) {
    __shared__ int fh[512];
    __shared__ int pp[512];
    __shared__ int cur[512];
    const int c = blockIdx.x;
    const int tid = threadIdx.x;
    const int n0 = c << 9;
    const int cbase = c * CAPB;                    // ebuf region base
    const int cend = cbase + ccur[c];              // + bucket count
    const int pbase = c * (CAPB + PADCAP);         // csr region base

    fh[tid] = 0;
    __syncthreads();
    for (int e = cbase + tid; e < cend; e += 512)
        atomicAdd(&fh[ebuf[e].x >> 17], 1);
    __syncthreads();

    int cnt = fh[tid];
    int p = (cnt + 7) & ~7;          // pad rows to multiple of 8
    pp[tid] = p;
    __syncthreads();
    #pragma unroll
    for (int off = 1; off < 512; off <<= 1) {
        int t = (tid >= off) ? pp[tid - off] : 0;
        __syncthreads();
        pp[tid] += t;
        __syncthreads();
    }
    int r = pbase + pp[tid] - p;   // padded exclusive position
    if (n0 + tid < N) {
        rstart[n0 + tid] = r;
        pdeg[n0 + tid] = p;
    }
    cur[tid] = r;
    __syncthreads();

    for (int e = cbase + tid; e < cend; e += 512) {
        uint2 u = ebuf[e];
        int fine = u.x >> 17;
        int pos = atomicAdd(&cur[fine], 1);
        csr[pos] = make_int2((int)(u.x & 0x1FFFF), (int)u.y);
    }
    __syncthreads();

    // dummy fill (src=0, w=0) up to padded end
    for (int k = cur[tid]; k < r + p; ++k)
        csr[k] = make_int2(0, 0);
}

// ---- Aggregation: NPW nodes per wave (split-wave) --------------------------
template <int F, int NPW, bool OBF>
__global__ __launch_bounds__(256) void agg_kernel(const ushort* __restrict__ sup,
                                                  const int* __restrict__ rstart,
                                                  const int* __restrict__ pdeg,
                                                  const int2* __restrict__ csr,
                                                  const float* __restrict__ bias,
                                                  void* __restrict__ outp, int N) {
    constexpr int LPN = 64 / NPW;    // lanes per node
    constexpr int LPR = F / 8;       // lanes per row
    static_assert(LPN / LPR == 2, "two slot-groups per node");
    const int lane = threadIdx.x & 63;
    const int wbase = ((blockIdx.x * 256 + threadIdx.x) >> 6) * NPW;
    if (wbase >= N) return;
    const int sub = lane / LPN;
    const int grp = (lane % LPN) / LPR;
    const int cl  = lane % LPR;
    const int node = wbase + sub;
    const bool nvalid = node < N;
    const int nidx = nvalid ? node : 0;
    const int rs = rstart[nidx];
    const int pd = nvalid ? pdeg[nidx] : 0;

    int pmax = pd;
    #pragma unroll
    for (int off = LPN; off < 64; off <<= 1)
        pmax = max(pmax, __shfl_xor(pmax, off));
    pmax = __builtin_amdgcn_readfirstlane(pmax);

    const ushort* rp = sup + cl * 8;
    float acc[8] = {0.f, 0.f, 0.f, 0.f, 0.f, 0.f, 0.f, 0.f};

    for (int j = 0; j < pmax; j += 16) {
        int2 m[8];
        #pragma unroll
        for (int t = 0; t < 8; ++t) {
            int slot = j + t * 2 + grp;
            bool ok = slot < pd;
            m[t] = csr[rs + (ok ? slot : 0)];
            if (!ok) m[t].y = 0;
        }
        uint4 v[8];
        #pragma unroll
        for (int t = 0; t < 8; ++t)
            v[t] = *(const uint4*)(rp + (size_t)m[t].x * F);
        #pragma unroll
        for (int t = 0; t < 8; ++t) {
            float w = __int_as_float(m[t].y);
            uint4 q = v[t];
            acc[0] = fmaf(bf_lo(q.x), w, acc[0]); acc[1] = fmaf(bf_hi(q.x), w, acc[1]);
            acc[2] = fmaf(bf_lo(q.y), w, acc[2]); acc[3] = fmaf(bf_hi(q.y), w, acc[3]);
            acc[4] = fmaf(bf_lo(q.z), w, acc[4]); acc[5] = fmaf(bf_hi(q.z), w, acc[5]);
            acc[6] = fmaf(bf_lo(q.w), w, acc[6]); acc[7] = fmaf(bf_hi(q.w), w, acc[7]);
        }
    }

    // fold the two slot-groups of each node (lanes differ by LPR)
    #pragma unroll
    for (int i = 0; i < 8; ++i) acc[i] += __shfl_xor(acc[i], LPR);

    if (grp == 0 && nvalid) {
        float4 b0 = ((const float4*)bias)[cl * 2 + 0];
        float4 b1 = ((const float4*)bias)[cl * 2 + 1];
        acc[0] = fmaxf(acc[0] + b0.x, 0.f); acc[1] = fmaxf(acc[1] + b0.y, 0.f);
        acc[2] = fmaxf(acc[2] + b0.z, 0.f); acc[3] = fmaxf(acc[3] + b0.w, 0.f);
        acc[4] = fmaxf(acc[4] + b1.x, 0.f); acc[5] = fmaxf(acc[5] + b1.y, 0.f);
        acc[6] = fmaxf(acc[6] + b1.z, 0.f); acc[7] = fmaxf(acc[7] + b1.w, 0.f);
        if (OBF) {
            uint4 o;
            o.x = (uint)f2bf(acc[0]) | ((uint)f2bf(acc[1]) << 16);
            o.y = (uint)f2bf(acc[2]) | ((uint)f2bf(acc[3]) << 16);
            o.z = (uint)f2bf(acc[4]) | ((uint)f2bf(acc[5]) << 16);
            o.w = (uint)f2bf(acc[6]) | ((uint)f2bf(acc[7]) << 16);
            ((uint4*)outp)[(size_t)node * LPR + cl] = o;
        } else {
            ((float4*)outp)[(size_t)node * LPR * 2 + cl * 2 + 0] =
                make_float4(acc[0], acc[1], acc[2], acc[3]);
            ((float4*)outp)[(size_t)node * LPR * 2 + cl * 2 + 1] =
                make_float4(acc[4], acc[5], acc[6], acc[7]);
        }
    }
}

extern "C" void kernel_launch(void* const* d_in, const int* in_sizes, int n_in,
                              void* d_out, int out_size, void* d_ws, size_t ws_size,
                              hipStream_t stream) {
    const float* x  = (const float*)d_in[0];
    const int*   ei = (const int*)d_in[1];
    const float* ew = (const float*)d_in[2];
    const float* W1 = (const float*)d_in[3];
    const float* b1 = (const float*)d_in[4];
    const float* W2 = (const float*)d_in[5];
    const float* b2 = (const float*)d_in[6];
    float* out = (float*)d_out;

    const int N = in_sizes[0] / 128;     // 100000
    const int E = in_sizes[2];           // 1600000
    const int* src = ei;
    const int* dst = ei + E;
    const int NCB = (N + 511) / 512;     // 196 coarse buckets (<= 256)
    const int GB = (N + 127) / 128;      // 782 gemm1 row tiles
    const int NBA = (E + 4095) / 4096;   // 391 binA blocks

    char* ws = (char*)d_ws;
    size_t o = 0;
    ushort* S      = (ushort*)(ws + o); o += (size_t)N * 128 * sizeof(ushort);
    ushort* H1b    = (ushort*)(ws + o); o += (size_t)N * 128 * sizeof(ushort);
    uint2*  ebuf   = (uint2*) (ws + o); o += (size_t)NCB * CAPB * sizeof(uint2);
    int2*   csr    = (int2*)  (ws + o); o += (size_t)NCB * (CAPB + PADCAP) * sizeof(int2);
    int*    rstart = (int*)   (ws + o); o += (size_t)N * sizeof(int);
    int*    pdeg   = (int*)   (ws + o); o += (size_t)N * sizeof(int);
    int*    ccur   = (int*)   (ws + o); o += 256 * sizeof(int);
    ushort* Wt1    = (ushort*)(ws + o); o += 128 * 128 * sizeof(ushort);
    ushort* Wt2    = (ushort*)(ws + o); o += 128 * 64 * sizeof(ushort);

    // ---- weights -> bf16 transposed; zero bump cursors ----
    wconv_kernel<<<96, 256, 0, stream>>>(W1, Wt1, W2, Wt2, ccur);

    // ---- fused front-end: binA-direct || gemm1 (all tiles) ----
    fused_kernel<<<NBA + GB, 256, 0, stream>>>(NBA, src, dst, ew, ccur,
                                               ebuf, E, x, Wt1, S, N);
    binB_kernel<<<NCB, 512, 0, stream>>>(ebuf, ccur, rstart, pdeg, csr, N);

    // ---- layer 1 aggregation ----
    agg_kernel<128, 2, true><<<(N + 7) / 8, 256, 0, stream>>>(S, rstart, pdeg, csr, b1, H1b, N);

    // ---- layer 2 ----
    gemm_mfma64<<<GB, 256, 0, stream>>>(H1b, Wt2, S, N);
    agg_kernel<64, 4, false><<<(N + 15) / 16, 256, 0, stream>>>(S, rstart, pdeg, csr, b2, out, N);
}